// Round 5
// baseline (665.639 us; speedup 1.0000x reference)
//
#include <hip/hip_runtime.h>
#include <hip/hip_bf16.h>

typedef __hip_bfloat16 bf16;
typedef __attribute__((ext_vector_type(8))) short bf16x8;
typedef __attribute__((ext_vector_type(4))) float f32x4;

#define MFMA16(a, b, c) __builtin_amdgcn_mfma_f32_16x16x32_bf16(a, b, c, 0, 0, 0)

// Problem constants (B=1)
#define HH 256
#define WW 256
#define DD 64
#define PP 128
#define NHEADS 8
#define DHEAD 64
#define NROWS 65536

// ---------------- NEW (atomic-free) ws layout, used when ws_size >= WS_NEED:
//   q   @ 0          (67108864 B bf16)
//   k   @ 67108864   (67108864)   -> reused as Oh after k_dots_s
//   v   @ 134217728  (67108864)
//   Ow  @ 201326592  (67108864)   bf16 h-major [n=h*256+w][512]
//   dp  @ 268435456  (8 slices x 2097152 = 16777216)  split-K dots
//   Wt_w@ 285212672 (196608) | Wt_h (196608) | Wo_w (65536) | Wo_h (65536)
//   P aliases q (q dead after k_dots_s).
#define WS_NEED 285736960ULL
// ---------------- FALLBACK layout (proven r4, 203.4 MB): q|k|v|dots(2MB).

// MFMA fragment conventions (verified m89/m91/m120):
//   A-frag: lane l holds A[m = l&15][k = (l>>4)*8 + t], t=0..7
//   B-frag: lane l holds B[n = l&15][k = (l>>4)*8 + t]
//   C/D   : lane l, reg r -> (col = l&15, row = (l>>4)*4 + r)
//   D[m][n] = sum_k A[m][k]*B[n][k]

__device__ __forceinline__ bf16x8 cvt8(const float* f) {
  bf16x8 r;
  bf16* h = (bf16*)&r;
#pragma unroll
  for (int i = 0; i < 8; i++) h[i] = __float2bfloat16(f[i]);
  return r;
}

// ================================================================ shared kernels

// QKV via MFMA; swap=1 -> write rows w-major (w*256+h).
__global__ void __launch_bounds__(256) k_qkv_mfma(const float* __restrict__ x,
                                                  const bf16* __restrict__ Wt,
                                                  bf16* __restrict__ q,
                                                  bf16* __restrict__ kk,
                                                  bf16* __restrict__ v,
                                                  int swap) {
  const int tid = threadIdx.x, lane = tid & 63, wv = tid >> 6;
  const int m16 = lane & 15, kq = lane >> 4;
  const int rowA = blockIdx.x * 64 + wv * 16 + m16;
  const int rowC0 = blockIdx.x * 64 + wv * 16 + kq * 4;

  const float* xr = x + (size_t)rowA * 64;
  float xf[8];
  bf16x8 af[2];
  *(float4*)&xf[0] = *(const float4*)(xr + kq * 8);
  *(float4*)&xf[4] = *(const float4*)(xr + kq * 8 + 4);
  af[0] = cvt8(xf);
  *(float4*)&xf[0] = *(const float4*)(xr + 32 + kq * 8);
  *(float4*)&xf[4] = *(const float4*)(xr + 32 + kq * 8 + 4);
  af[1] = cvt8(xf);

  size_t rbase[4];
#pragma unroll
  for (int r = 0; r < 4; r++) {
    const int rc = rowC0 + r;
    const int rr = swap ? (((rc & 255) << 8) | (rc >> 8)) : rc;
    rbase[r] = (size_t)rr * 512;
  }

#pragma unroll 1
  for (int cg = 0; cg < 12; cg++) {
    bf16* dst = (cg < 4) ? q : (cg < 8) ? kk : v;
    const int cbase = (cg & 3) * 128;
#pragma unroll
    for (int ct = 0; ct < 8; ct++) {
      const bf16* wp = Wt + (size_t)(cg * 128 + ct * 16 + m16) * 64 + kq * 8;
      const bf16x8 b0 = *(const bf16x8*)wp;
      const bf16x8 b1 = *(const bf16x8*)(wp + 32);
      f32x4 a = (f32x4){0.f, 0.f, 0.f, 0.f};
      a = MFMA16(af[0], b0, a);
      a = MFMA16(af[1], b1, a);
      const int cloc = cbase + ct * 16 + m16;
#pragma unroll
      for (int r = 0; r < 4; r++)
        dst[rbase[r] + cloc] = __float2bfloat16(a[r]);
    }
  }
}

// pair bias: LN + @W_pair, wave per (i,j); adds into slice-0 (or dots)
__global__ void __launch_bounds__(256) k_pb(const float* __restrict__ pb,
                                            const float* __restrict__ g,
                                            const float* __restrict__ bb,
                                            const float* __restrict__ Wp,
                                            float* __restrict__ dots) {
  __shared__ float sn[4][128];
  const int tid = threadIdx.x, lane = tid & 63, wv = tid >> 6;
  const size_t ij = (size_t)blockIdx.x * 4 + wv;
  const float2 xv = *(const float2*)(pb + ij * 128 + lane * 2);

  float s = xv.x + xv.y;
#pragma unroll
  for (int o = 1; o < 64; o <<= 1) s += __shfl_xor(s, o);
  const float mu = s * (1.f / 128.f);
  const float d0 = xv.x - mu, d1 = xv.y - mu;
  float s2 = d0 * d0 + d1 * d1;
#pragma unroll
  for (int o = 1; o < 64; o <<= 1) s2 += __shfl_xor(s2, o);
  const float inv = rsqrtf(s2 * (1.f / 128.f) + 1e-5f);

  sn[wv][lane * 2 + 0] = d0 * inv * g[lane * 2 + 0] + bb[lane * 2 + 0];
  sn[wv][lane * 2 + 1] = d1 * inv * g[lane * 2 + 1] + bb[lane * 2 + 1];

  const int h = lane & 7, gp = lane >> 3;
  float a = 0.f;
#pragma unroll
  for (int p0 = 0; p0 < 16; p0++) {
    const int p = gp * 16 + p0;
    a += sn[wv][p] * Wp[p * 8 + h];
  }
  a += __shfl_xor(a, 8);
  a += __shfl_xor(a, 16);
  a += __shfl_xor(a, 32);
  if (lane < 8) dots[(size_t)h * 65536 + ij] += a;
}

// ================================================================ NEW-PATH kernels

// weight prep: Wq|Wkv transposed (bf16 [1536][64]) + Wout transposed (bf16 [64][512])
__global__ void __launch_bounds__(256) k_wt2(const float* __restrict__ Wq_w,
                                             const float* __restrict__ Wkv_w,
                                             const float* __restrict__ Wq_h,
                                             const float* __restrict__ Wkv_h,
                                             const float* __restrict__ Wout_w,
                                             const float* __restrict__ Wout_h,
                                             bf16* __restrict__ Wt_w, bf16* __restrict__ Wt_h,
                                             bf16* __restrict__ Wo_w, bf16* __restrict__ Wo_h) {
  int idx = blockIdx.x * 256 + threadIdx.x;  // [0, 262144)
  if (idx < 196608) {
    const float* Wq = Wq_w;
    const float* Wkv = Wkv_w;
    bf16* dst = Wt_w;
    if (idx >= 98304) { idx -= 98304; Wq = Wq_h; Wkv = Wkv_h; dst = Wt_h; }
    const int k = idx / 1536, c = idx - k * 1536;
    const float val = (c < 512) ? Wq[k * 512 + c] : Wkv[k * 1024 + (c - 512)];
    dst[(size_t)c * 64 + k] = __float2bfloat16(val);
  } else {
    idx -= 196608;  // [0, 65536)
    const float* W = Wout_w;
    bf16* dst = Wo_w;
    if (idx >= 32768) { idx -= 32768; W = Wout_h; dst = Wo_h; }
    const int c = idx >> 9, d = idx & 511;
    dst[idx] = __float2bfloat16(W[d * 64 + c]);  // dst[c][d] = W[d][c]
  }
}

// width attention, NO projection, NO atomics. Inputs w-major. Writes Ow h-major bf16.
// LDS 53248: Vt[64][256] swizzled @0 | Ps[wave][64][40] @32768.
__global__ void __launch_bounds__(256, 2)
k_width_attn_o(const bf16* __restrict__ q, const bf16* __restrict__ kk,
               const bf16* __restrict__ v, bf16* __restrict__ Ow) {
  __shared__ __align__(16) char smem[53248];
  bf16* Vt = (bf16*)smem;
  const int w = blockIdx.x, head = blockIdx.y;
  const int tid = threadIdx.x, lane = tid & 63, wv = tid >> 6;
  bf16* Ps = (bf16*)(smem + 32768 + wv * 5120);
  const int m16 = lane & 15, kq = lane >> 4;

  {  // Vt[d][jOct^(d&7)][j&7] = V[j][d]
    const bf16* src = v + ((size_t)(w * 256 + tid) * 512 + head * 64);
    uint4 rr[8];
#pragma unroll
    for (int c = 0; c < 8; c++) rr[c] = ((const uint4*)src)[c];
    const int jl = tid & 7, jh = tid >> 3;
#pragma unroll
    for (int c = 0; c < 8; c++) {
      const bf16* e = (const bf16*)&rr[c];
#pragma unroll
      for (int t = 0; t < 8; t++) {
        const int d = c * 8 + t;
        Vt[d * 256 + ((jh ^ (d & 7)) << 3) + jl] = e[t];
      }
    }
  }
  bf16x8 qf[4][2];
  const int i0 = wv * 64;
#pragma unroll
  for (int it = 0; it < 4; it++) {
    const bf16* b = q + ((size_t)(w * 256 + i0 + it * 16 + m16) * 512 + head * 64 + kq * 8);
    qf[it][0] = *(const bf16x8*)b;
    qf[it][1] = *(const bf16x8*)(b + 32);
  }
  __syncthreads();

  f32x4 acc[4][4];
#pragma unroll
  for (int a = 0; a < 4; a++)
#pragma unroll
    for (int b = 0; b < 4; b++) acc[a][b] = (f32x4){0.f, 0.f, 0.f, 0.f};
  float rsum[4][4];
#pragma unroll
  for (int a = 0; a < 4; a++)
#pragma unroll
    for (int r = 0; r < 4; r++) rsum[a][r] = 0.f;

  auto loadK = [&](int jc, bf16x8 kf[2][2]) {
#pragma unroll
    for (int jt = 0; jt < 2; jt++) {
      const bf16* b = kk + ((size_t)(w * 256 + jc * 32 + jt * 16 + m16) * 512 + head * 64 + kq * 8);
      kf[jt][0] = *(const bf16x8*)b;
      kf[jt][1] = *(const bf16x8*)(b + 32);
    }
  };
  bf16x8 kcur[2][2];
  loadK(0, kcur);

#pragma unroll 1
  for (int jc = 0; jc < 8; jc++) {
    bf16x8 knext[2][2];
    if (jc < 7) loadK(jc + 1, knext);
#pragma unroll
    for (int it = 0; it < 4; it++)
#pragma unroll
      for (int jt = 0; jt < 2; jt++) {
        f32x4 s = (f32x4){0.f, 0.f, 0.f, 0.f};
        s = MFMA16(qf[it][0], kcur[jt][0], s);
        s = MFMA16(qf[it][1], kcur[jt][1], s);
#pragma unroll
        for (int r = 0; r < 4; r++) {
          float p = __expf(s[r] * 0.125f);
          rsum[it][r] += p;
          Ps[(it * 16 + kq * 4 + r) * 40 + jt * 16 + m16] = __float2bfloat16(p);
        }
      }
    bf16x8 pf[4], vf[4];
#pragma unroll
    for (int it = 0; it < 4; it++)
      pf[it] = *(const bf16x8*)&Ps[(it * 16 + m16) * 40 + kq * 8];
#pragma unroll
    for (int dt = 0; dt < 4; dt++)
      vf[dt] = *(const bf16x8*)&Vt[(dt * 16 + m16) * 256 + (((jc * 4 + kq) ^ (m16 & 7)) << 3)];
#pragma unroll
    for (int it = 0; it < 4; it++)
#pragma unroll
      for (int dt = 0; dt < 4; dt++) acc[it][dt] = MFMA16(pf[it], vf[dt], acc[it][dt]);
    if (jc < 7) {
#pragma unroll
      for (int jt = 0; jt < 2; jt++) {
        kcur[jt][0] = knext[jt][0];
        kcur[jt][1] = knext[jt][1];
      }
    }
  }

#pragma unroll
  for (int it = 0; it < 4; it++)
#pragma unroll
    for (int r = 0; r < 4; r++) {
      float s = rsum[it][r];
      s += __shfl_xor(s, 1); s += __shfl_xor(s, 2);
      s += __shfl_xor(s, 4); s += __shfl_xor(s, 8);
      rsum[it][r] = 1.f / s;
    }
  // O (normalized) -> Ow h-major, plain posted stores (scattered rows, contiguous 32B/dt)
#pragma unroll
  for (int it = 0; it < 4; it++)
#pragma unroll
    for (int dt = 0; dt < 4; dt++)
#pragma unroll
      for (int r = 0; r < 4; r++) {
        const int i = i0 + it * 16 + kq * 4 + r;  // = h
        Ow[((size_t)(i * 256 + w)) * 512 + head * 64 + dt * 16 + m16] =
            __float2bfloat16(acc[it][dt][r] * rsum[it][r]);
      }
}

// height tied dots, split-K into 8 private slices, plain stores.
// grid (16 tiles 64x64, 8 heads, 8 rc), block 256 = 4 waves (16 i-rows each).
__global__ void __launch_bounds__(256, 2)
k_dots_s(const bf16* __restrict__ q, const bf16* __restrict__ kk, float* __restrict__ dp) {
  __shared__ __align__(16) bf16 Qs[64 * 72];
  __shared__ __align__(16) bf16 Ks[64 * 72];
  const int tile = blockIdx.x, head = blockIdx.y, rc = blockIdx.z;
  const int i0 = (tile >> 2) * 64, j0 = (tile & 3) * 64;
  const int tid = threadIdx.x, lane = tid & 63, wv = tid >> 6;
  const int m16 = lane & 15, kq = lane >> 4;
  float* slice = dp + (size_t)rc * 524288 + (size_t)head * 65536;

  f32x4 acc[4];
#pragma unroll
  for (int b = 0; b < 4; b++) acc[b] = (f32x4){0.f, 0.f, 0.f, 0.f};

  const int row = tid >> 2, ch = (tid & 3) * 16;
#pragma unroll 1
  for (int rr = 0; rr < 32; rr++) {
    const int rrow = rc * 32 + rr;
    __syncthreads();
    {
      const bf16* qsrc = q + ((size_t)(rrow * 256 + i0 + row) * 512 + head * 64 + ch);
      const bf16* ksrc = kk + ((size_t)(rrow * 256 + j0 + row) * 512 + head * 64 + ch);
      *(uint4*)&Qs[row * 72 + ch] = *(const uint4*)qsrc;
      *(uint4*)&Qs[row * 72 + ch + 8] = *(const uint4*)(qsrc + 8);
      *(uint4*)&Ks[row * 72 + ch] = *(const uint4*)ksrc;
      *(uint4*)&Ks[row * 72 + ch + 8] = *(const uint4*)(ksrc + 8);
    }
    __syncthreads();
#pragma unroll
    for (int ks = 0; ks < 2; ks++) {
      bf16x8 af = *(const bf16x8*)&Qs[(wv * 16 + m16) * 72 + ks * 32 + kq * 8];
      bf16x8 bfr[4];
#pragma unroll
      for (int jt = 0; jt < 4; jt++)
        bfr[jt] = *(const bf16x8*)&Ks[(jt * 16 + m16) * 72 + ks * 32 + kq * 8];
#pragma unroll
      for (int jt = 0; jt < 4; jt++) acc[jt] = MFMA16(af, bfr[jt], acc[jt]);
    }
  }
  const float sc = 1.f / 128.f;
#pragma unroll
  for (int jt = 0; jt < 4; jt++)
#pragma unroll
    for (int r = 0; r < 4; r++)
      slice[(size_t)(i0 + wv * 16 + kq * 4 + r) * 256 + j0 + jt * 16 + m16] = acc[jt][r] * sc;
}

// softmax over j, summing 8 split-K slices (slice 0 already carries pair bias)
__global__ void __launch_bounds__(256) k_softmax8(const float* __restrict__ dp,
                                                  bf16* __restrict__ P) {
  __shared__ float red[4];
  const int i = blockIdx.x, head = blockIdx.y, t = threadIdx.x;
  const size_t base = (size_t)head * 65536 + i * 256 + t;
  float lg = 0.f;
#pragma unroll
  for (int s = 0; s < 8; s++) lg += dp[(size_t)s * 524288 + base];
  const float e = __expf(lg);
  float s = e;
#pragma unroll
  for (int o = 1; o < 64; o <<= 1) s += __shfl_xor(s, o);
  if ((t & 63) == 0) red[t >> 6] = s;
  __syncthreads();
  const float S = red[0] + red[1] + red[2] + red[3];
  P[base] = __float2bfloat16(e / S);
}

// height PV, NO projection, NO atomics. Writes Oh (h-major) bf16.
// LDS 32768: Vt[64][256] swizzled.
__global__ void __launch_bounds__(256, 2)
k_h_pv_o(const bf16* __restrict__ P, const bf16* __restrict__ v, bf16* __restrict__ Oh) {
  __shared__ __align__(16) bf16 Vt[64 * 256];
  const int r = blockIdx.x, head = blockIdx.y;
  const int tid = threadIdx.x, lane = tid & 63, wv = tid >> 6;
  const int m16 = lane & 15, kq = lane >> 4;

  {
    const bf16* src = v + ((size_t)(r * 256 + tid) * 512 + head * 64);
    uint4 rr[8];
#pragma unroll
    for (int c = 0; c < 8; c++) rr[c] = ((const uint4*)src)[c];
    const int jl = tid & 7, jh = tid >> 3;
#pragma unroll
    for (int c = 0; c < 8; c++) {
      const bf16* e = (const bf16*)&rr[c];
#pragma unroll
      for (int t = 0; t < 8; t++) {
        const int d = c * 8 + t;
        Vt[d * 256 + ((jh ^ (d & 7)) << 3) + jl] = e[t];
      }
    }
  }

  const bf16* Pb = P + (size_t)head * 65536;
  const int i0 = wv * 64;
  auto loadP = [&](int ks, bf16x8 pf[4]) {
#pragma unroll
    for (int it = 0; it < 4; it++)
      pf[it] = *(const bf16x8*)(Pb + (size_t)(i0 + it * 16 + m16) * 256 + ks * 32 + kq * 8);
  };
  bf16x8 pcur[4];
  loadP(0, pcur);
  __syncthreads();

  f32x4 acc[4][4];
#pragma unroll
  for (int a = 0; a < 4; a++)
#pragma unroll
    for (int b = 0; b < 4; b++) acc[a][b] = (f32x4){0.f, 0.f, 0.f, 0.f};

#pragma unroll 1
  for (int ks = 0; ks < 8; ks++) {
    bf16x8 pnext[4];
    if (ks < 7) loadP(ks + 1, pnext);
    bf16x8 vf[4];
#pragma unroll
    for (int dt = 0; dt < 4; dt++)
      vf[dt] = *(const bf16x8*)&Vt[(dt * 16 + m16) * 256 + (((ks * 4 + kq) ^ (m16 & 7)) << 3)];
#pragma unroll
    for (int it = 0; it < 4; it++)
#pragma unroll
      for (int dt = 0; dt < 4; dt++) acc[it][dt] = MFMA16(pcur[it], vf[dt], acc[it][dt]);
    if (ks < 7) {
#pragma unroll
      for (int it = 0; it < 4; it++) pcur[it] = pnext[it];
    }
  }
#pragma unroll
  for (int it = 0; it < 4; it++)
#pragma unroll
    for (int dt = 0; dt < 4; dt++)
#pragma unroll
      for (int r2 = 0; r2 < 4; r2++) {
        const int i = i0 + it * 16 + kq * 4 + r2;  // w position
        Oh[((size_t)(r * 256 + i)) * 512 + head * 64 + dt * 16 + m16] =
            __float2bfloat16(acc[it][dt][r2]);
      }
}

// final fused projection: out = 0.5*(Ow@Wout_w + Oh@Wout_h) + 0.5*(bw+bh)
// grid 1024 (64 rows each), block 256 = 4 waves x 16 rows. No LDS.
__global__ void __launch_bounds__(256) k_outproj(const bf16* __restrict__ Ow,
                                                 const bf16* __restrict__ Oh,
                                                 const bf16* __restrict__ Wow,  // [64][512]
                                                 const bf16* __restrict__ Woh,
                                                 const float* __restrict__ bw,
                                                 const float* __restrict__ bh,
                                                 float* __restrict__ out) {
  const int tid = threadIdx.x, lane = tid & 63, wv = tid >> 6;
  const int m16 = lane & 15, kq = lane >> 4;
  const int nA = blockIdx.x * 64 + wv * 16 + m16;

  const bf16* aw = Ow + (size_t)nA * 512 + kq * 8;
  const bf16* ah = Oh + (size_t)nA * 512 + kq * 8;

  f32x4 acc[4];
#pragma unroll
  for (int ct = 0; ct < 4; ct++) acc[ct] = (f32x4){0.f, 0.f, 0.f, 0.f};

#pragma unroll 1
  for (int kc = 0; kc < 16; kc++) {
    const bf16x8 afw = *(const bf16x8*)(aw + kc * 32);
    const bf16x8 afh = *(const bf16x8*)(ah + kc * 32);
#pragma unroll
    for (int ct = 0; ct < 4; ct++) {
      const bf16x8 bfw = *(const bf16x8*)(Wow + (size_t)(ct * 16 + m16) * 512 + kc * 32 + kq * 8);
      const bf16x8 bfh = *(const bf16x8*)(Woh + (size_t)(ct * 16 + m16) * 512 + kc * 32 + kq * 8);
      acc[ct] = MFMA16(afw, bfw, acc[ct]);
      acc[ct] = MFMA16(afh, bfh, acc[ct]);
    }
  }
  const int n0 = blockIdx.x * 64 + wv * 16 + kq * 4;
#pragma unroll
  for (int ct = 0; ct < 4; ct++) {
    const int c = ct * 16 + m16;
    const float bias = 0.5f * (bw[c] + bh[c]);
#pragma unroll
    for (int r = 0; r < 4; r++)
      out[(size_t)(n0 + r) * 64 + c] = 0.5f * acc[ct][r] + bias;
  }
}

// ================================================================ FALLBACK kernels (proven r4)

__global__ void __launch_bounds__(256) k_init_out(const float* __restrict__ bw,
                                                  const float* __restrict__ bh,
                                                  float* __restrict__ out) {
  int idx = blockIdx.x * 256 + threadIdx.x;
  out[idx] = 0.5f * (bw[idx & 63] + bh[idx & 63]);
}

__global__ void __launch_bounds__(256) k_wt(const float* __restrict__ Wq_w,
                                            const float* __restrict__ Wkv_w,
                                            const float* __restrict__ Wq_h,
                                            const float* __restrict__ Wkv_h,
                                            bf16* __restrict__ Wt_w,
                                            bf16* __restrict__ Wt_h) {
  int idx = blockIdx.x * 256 + threadIdx.x;
  const float* Wq = Wq_w;
  const float* Wkv = Wkv_w;
  bf16* dst = Wt_w;
  if (idx >= 98304) { idx -= 98304; Wq = Wq_h; Wkv = Wkv_h; dst = Wt_h; }
  const int k = idx / 1536, c = idx - k * 1536;
  const float val = (c < 512) ? Wq[k * 512 + c] : Wkv[k * 1024 + (c - 512)];
  dst[(size_t)c * 64 + k] = __float2bfloat16(val);
}

__global__ void __launch_bounds__(256, 2)
k_width_attn(const bf16* __restrict__ q, const bf16* __restrict__ kk,
             const bf16* __restrict__ v, const float* __restrict__ Wout,
             float* __restrict__ out) {
  __shared__ __align__(16) char smem[53248];
  bf16* Vt = (bf16*)smem;
  const int w = blockIdx.x, head = blockIdx.y;
  const int tid = threadIdx.x, lane = tid & 63, wv = tid >> 6;
  bf16* Ps  = (bf16*)(smem + 32768 + wv * 5120);
  bf16* Ot  = (bf16*)(smem + (size_t)wv * 9216);
  bf16* Wtr = (bf16*)(smem + 36864);
  const int m16 = lane & 15, kq = lane >> 4;

  {
    const bf16* src = v + ((size_t)(w * 256 + tid) * 512 + head * 64);
    uint4 rr[8];
#pragma unroll
    for (int c = 0; c < 8; c++) rr[c] = ((const uint4*)src)[c];
    const int jl = tid & 7, jh = tid >> 3;
#pragma unroll
    for (int c = 0; c < 8; c++) {
      const bf16* e = (const bf16*)&rr[c];
#pragma unroll
      for (int t = 0; t < 8; t++) {
        const int d = c * 8 + t;
        Vt[d * 256 + ((jh ^ (d & 7)) << 3) + jl] = e[t];
      }
    }
  }
  bf16x8 qf[4][2];
  const int i0 = wv * 64;
#pragma unroll
  for (int it = 0; it < 4; it++) {
    const bf16* b = q + ((size_t)(w * 256 + i0 + it * 16 + m16) * 512 + head * 64 + kq * 8);
    qf[it][0] = *(const bf16x8*)b;
    qf[it][1] = *(const bf16x8*)(b + 32);
  }
  __syncthreads();

  f32x4 acc[4][4];
#pragma unroll
  for (int a = 0; a < 4; a++)
#pragma unroll
    for (int b = 0; b < 4; b++) acc[a][b] = (f32x4){0.f, 0.f, 0.f, 0.f};
  float rsum[4][4];
#pragma unroll
  for (int a = 0; a < 4; a++)
#pragma unroll
    for (int r = 0; r < 4; r++) rsum[a][r] = 0.f;

  auto loadK = [&](int jc, bf16x8 kf[2][2]) {
#pragma unroll
    for (int jt = 0; jt < 2; jt++) {
      const bf16* b = kk + ((size_t)(w * 256 + jc * 32 + jt * 16 + m16) * 512 + head * 64 + kq * 8);
      kf[jt][0] = *(const bf16x8*)b;
      kf[jt][1] = *(const bf16x8*)(b + 32);
    }
  };
  bf16x8 kcur[2][2];
  loadK(0, kcur);

#pragma unroll 1
  for (int jc = 0; jc < 8; jc++) {
    bf16x8 knext[2][2];
    if (jc < 7) loadK(jc + 1, knext);
#pragma unroll
    for (int it = 0; it < 4; it++)
#pragma unroll
      for (int jt = 0; jt < 2; jt++) {
        f32x4 s = (f32x4){0.f, 0.f, 0.f, 0.f};
        s = MFMA16(qf[it][0], kcur[jt][0], s);
        s = MFMA16(qf[it][1], kcur[jt][1], s);
#pragma unroll
        for (int r = 0; r < 4; r++) {
          float p = __expf(s[r] * 0.125f);
          rsum[it][r] += p;
          Ps[(it * 16 + kq * 4 + r) * 40 + jt * 16 + m16] = __float2bfloat16(p);
        }
      }
    bf16x8 pf[4], vf[4];
#pragma unroll
    for (int it = 0; it < 4; it++)
      pf[it] = *(const bf16x8*)&Ps[(it * 16 + m16) * 40 + kq * 8];
#pragma unroll
    for (int dt = 0; dt < 4; dt++)
      vf[dt] = *(const bf16x8*)&Vt[(dt * 16 + m16) * 256 + (((jc * 4 + kq) ^ (m16 & 7)) << 3)];
#pragma unroll
    for (int it = 0; it < 4; it++)
#pragma unroll
      for (int dt = 0; dt < 4; dt++) acc[it][dt] = MFMA16(pf[it], vf[dt], acc[it][dt]);
    if (jc < 7) {
#pragma unroll
      for (int jt = 0; jt < 2; jt++) {
        kcur[jt][0] = knext[jt][0];
        kcur[jt][1] = knext[jt][1];
      }
    }
  }

#pragma unroll
  for (int it = 0; it < 4; it++)
#pragma unroll
    for (int r = 0; r < 4; r++) {
      float s = rsum[it][r];
      s += __shfl_xor(s, 1); s += __shfl_xor(s, 2);
      s += __shfl_xor(s, 4); s += __shfl_xor(s, 8);
      rsum[it][r] = 1.f / s;
    }
  __syncthreads();
#pragma unroll
  for (int it = 0; it < 4; it++)
#pragma unroll
    for (int dt = 0; dt < 4; dt++)
#pragma unroll
      for (int r = 0; r < 4; r++)
        Ot[(it * 16 + kq * 4 + r) * 72 + dt * 16 + m16] =
            __float2bfloat16(acc[it][dt][r] * rsum[it][r]);
#pragma unroll
  for (int s = 0; s < 16; s++) {
    int idx = s * 256 + tid;
    int d = idx >> 6, c = idx & 63;
    Wtr[c * 72 + d] = __float2bfloat16(Wout[(head * 64 + d) * 64 + c]);
  }
  __syncthreads();

  bf16x8 of[4][2], wf[4][2];
#pragma unroll
  for (int it = 0; it < 4; it++) {
    of[it][0] = *(const bf16x8*)&Ot[(it * 16 + m16) * 72 + kq * 8];
    of[it][1] = *(const bf16x8*)&Ot[(it * 16 + m16) * 72 + 32 + kq * 8];
  }
#pragma unroll
  for (int ct = 0; ct < 4; ct++) {
    wf[ct][0] = *(const bf16x8*)&Wtr[(ct * 16 + m16) * 72 + kq * 8];
    wf[ct][1] = *(const bf16x8*)&Wtr[(ct * 16 + m16) * 72 + 32 + kq * 8];
  }
#pragma unroll
  for (int it = 0; it < 4; it++)
#pragma unroll
    for (int ct = 0; ct < 4; ct++) {
      f32x4 c2 = (f32x4){0.f, 0.f, 0.f, 0.f};
      c2 = MFMA16(of[it][0], wf[ct][0], c2);
      c2 = MFMA16(of[it][1], wf[ct][1], c2);
#pragma unroll
      for (int r = 0; r < 4; r++) {
        int i = i0 + it * 16 + kq * 4 + r;
        atomicAdd(&out[(size_t)(i * 256 + w) * 64 + ct * 16 + m16], 0.5f * c2[r]);
      }
    }
}

__global__ void __launch_bounds__(256, 2)
k_dots(const bf16* __restrict__ q, const bf16* __restrict__ kk, float* __restrict__ dots) {
  __shared__ __align__(16) char smem[36864];
  bf16* Qs = (bf16*)smem;
  bf16* Ks = (bf16*)(smem + 18432);
  const int tile = blockIdx.x, head = blockIdx.y, rc = blockIdx.z;
  const int i0 = (tile >> 1) * 128, j0 = (tile & 1) * 128;
  const int tid = threadIdx.x, lane = tid & 63, wv = tid >> 6;
  const int m16 = lane & 15, kq = lane >> 4;
  const int ioff = wv * 32;

  f32x4 acc[2][8];
#pragma unroll
  for (int a = 0; a < 2; a++)
#pragma unroll
    for (int b = 0; b < 8; b++) acc[a][b] = (f32x4){0.f, 0.f, 0.f, 0.f};

#pragma unroll 1
  for (int rr = 0; rr < 16; rr++) {
    const int rrow = rc * 16 + rr;
    __syncthreads();
#pragma unroll
    for (int s = 0; s < 4; s++) {
      int idx = s * 256 + tid;
      int row = idx >> 3, ch = idx & 7;
      *(uint4*)&Qs[row * 72 + ch * 8] =
          *(const uint4*)(q + ((size_t)(rrow * 256 + i0 + row) * 512 + head * 64 + ch * 8));
      *(uint4*)&Ks[row * 72 + ch * 8] =
          *(const uint4*)(kk + ((size_t)(rrow * 256 + j0 + row) * 512 + head * 64 + ch * 8));
    }
    __syncthreads();
#pragma unroll
    for (int ks = 0; ks < 2; ks++) {
      bf16x8 af[2], bfr[8];
#pragma unroll
      for (int it = 0; it < 2; it++)
        af[it] = *(const bf16x8*)&Qs[(ioff + it * 16 + m16) * 72 + ks * 32 + kq * 8];
#pragma unroll
      for (int jt = 0; jt < 8; jt++)
        bfr[jt] = *(const bf16x8*)&Ks[(jt * 16 + m16) * 72 + ks * 32 + kq * 8];
#pragma unroll
      for (int it = 0; it < 2; it++)
#pragma unroll
        for (int jt = 0; jt < 8; jt++) acc[it][jt] = MFMA16(af[it], bfr[jt], acc[it][jt]);
    }
  }

  const float sc = 1.f / 128.f;
#pragma unroll
  for (int it = 0; it < 2; it++)
#pragma unroll
    for (int jt = 0; jt < 8; jt++)
#pragma unroll
      for (int r = 0; r < 4; r++) {
        int i = i0 + ioff + it * 16 + kq * 4 + r;
        int j = j0 + jt * 16 + m16;
        atomicAdd(&dots[(size_t)head * 65536 + i * 256 + j], acc[it][jt][r] * sc);
      }
}

__global__ void __launch_bounds__(256) k_softmax(const float* __restrict__ dots,
                                                 bf16* __restrict__ P) {
  __shared__ float red[4];
  const int i = blockIdx.x, head = blockIdx.y, t = threadIdx.x;
  const size_t base = (size_t)head * 65536 + i * 256;
  const float e = __expf(dots[base + t]);
  float s = e;
#pragma unroll
  for (int o = 1; o < 64; o <<= 1) s += __shfl_xor(s, o);
  if ((t & 63) == 0) red[t >> 6] = s;
  __syncthreads();
  const float S = red[0] + red[1] + red[2] + red[3];
  P[base + t] = __float2bfloat16(e / S);
}

__global__ void __launch_bounds__(256, 2)
k_h_pv(const bf16* __restrict__ P, const bf16* __restrict__ v,
       const float* __restrict__ Wout, float* __restrict__ out) {
  __shared__ __align__(16) char smem[46080];
  bf16* Vt  = (bf16*)smem;
  bf16* Wtr = (bf16*)(smem + 36864);
  const int r = blockIdx.x, head = blockIdx.y;
  const int tid = threadIdx.x, lane = tid & 63, wv = tid >> 6;
  bf16* Ot = (bf16*)(smem + (size_t)wv * 9216);
  const int m16 = lane & 15, kq = lane >> 4;

  {
    const bf16* src = v + ((size_t)(r * 256 + tid) * 512 + head * 64);
    uint4 rr[8];
#pragma unroll
    for (int c = 0; c < 8; c++) rr[c] = ((const uint4*)src)[c];
    const int jl = tid & 7, jh = tid >> 3;
#pragma unroll
    for (int c = 0; c < 8; c++) {
      const bf16* e = (const bf16*)&rr[c];
#pragma unroll
      for (int t = 0; t < 8; t++) {
        const int d = c * 8 + t;
        Vt[d * 256 + ((jh ^ (d & 7)) << 3) + jl] = e[t];
      }
    }
  }

  const bf16* Pb = P + (size_t)head * 65536;
  const int i0 = wv * 64;
  auto loadP = [&](int ks, bf16x8 pf[4]) {
#pragma unroll
    for (int it = 0; it < 4; it++)
      pf[it] = *(const bf16x8*)(Pb + (size_t)(i0 + it * 16 + m16) * 256 + ks * 32 + kq * 8);
  };
  bf16x8 pcur[4];
  loadP(0, pcur);
  __syncthreads();

  f32x4 acc[4][4];
#pragma unroll
  for (int a = 0; a < 4; a++)
#pragma unroll
    for (int b = 0; b < 4; b++) acc[a][b] = (f32x4){0.f, 0.f, 0.f, 0.f};

#pragma unroll 1
  for (int ks = 0; ks < 8; ks++) {
    bf16x8 pnext[4];
    if (ks < 7) loadP(ks + 1, pnext);
    bf16x8 vf[4];
#pragma unroll
    for (int dt = 0; dt < 4; dt++)
      vf[dt] = *(const bf16x8*)&Vt[(dt * 16 + m16) * 256 + (((ks * 4 + kq) ^ (m16 & 7)) << 3)];
#pragma unroll
    for (int it = 0; it < 4; it++)
#pragma unroll
      for (int dt = 0; dt < 4; dt++) acc[it][dt] = MFMA16(pcur[it], vf[dt], acc[it][dt]);
    if (ks < 7) {
#pragma unroll
      for (int it = 0; it < 4; it++) pcur[it] = pnext[it];
    }
  }
  __syncthreads();
#pragma unroll
  for (int it = 0; it < 4; it++)
#pragma unroll
    for (int dt = 0; dt < 4; dt++)
#pragma unroll
      for (int r2 = 0; r2 < 4; r2++)
        Ot[(it * 16 + kq * 4 + r2) * 72 + dt * 16 + m16] = __float2bfloat16(acc[it][dt][r2]);
#pragma unroll
  for (int s = 0; s < 16; s++) {
    int idx = s * 256 + tid;
    int d = idx >> 6, c = idx & 63;
    Wtr[c * 72 + d] = __float2bfloat16(Wout[(head * 64 + d) * 64 + c]);
  }
  __syncthreads();

  bf16x8 of[4][2], wf[4][2];
#pragma unroll
  for (int it = 0; it < 4; it++) {
    of[it][0] = *(const bf16x8*)&Ot[(it * 16 + m16) * 72 + kq * 8];
    of[it][1] = *(const bf16x8*)&Ot[(it * 16 + m16) * 72 + 32 + kq * 8];
  }
#pragma unroll
  for (int ct = 0; ct < 4; ct++) {
    wf[ct][0] = *(const bf16x8*)&Wtr[(ct * 16 + m16) * 72 + kq * 8];
    wf[ct][1] = *(const bf16x8*)&Wtr[(ct * 16 + m16) * 72 + 32 + kq * 8];
  }
#pragma unroll
  for (int it = 0; it < 4; it++)
#pragma unroll
    for (int ct = 0; ct < 4; ct++) {
      f32x4 c2 = (f32x4){0.f, 0.f, 0.f, 0.f};
      c2 = MFMA16(of[it][0], wf[ct][0], c2);
      c2 = MFMA16(of[it][1], wf[ct][1], c2);
#pragma unroll
      for (int r2 = 0; r2 < 4; r2++) {
        int i = i0 + it * 16 + kq * 4 + r2;
        atomicAdd(&out[(size_t)(r * 256 + i) * 64 + ct * 16 + m16], 0.5f * c2[r2]);
      }
    }
}

// ================================================================ launch
extern "C" void kernel_launch(void* const* d_in, const int* in_sizes, int n_in,
                              void* d_out, int out_size, void* d_ws, size_t ws_size,
                              hipStream_t stream) {
  const float* x      = (const float*)d_in[0];
  const float* pair   = (const float*)d_in[1];
  const float* Wq_w   = (const float*)d_in[2];
  const float* Wkv_w  = (const float*)d_in[3];
  const float* Wout_w = (const float*)d_in[4];
  const float* bout_w = (const float*)d_in[5];
  const float* Wq_h   = (const float*)d_in[6];
  const float* Wkv_h  = (const float*)d_in[7];
  const float* Wout_h = (const float*)d_in[8];
  const float* bout_h = (const float*)d_in[9];
  const float* ln_g   = (const float*)d_in[10];
  const float* ln_b   = (const float*)d_in[11];
  const float* W_pair = (const float*)d_in[12];
  float* out = (float*)d_out;

  char* ws = (char*)d_ws;
  const size_t NE = (size_t)NROWS * 512;
  bf16* q = (bf16*)ws;
  bf16* k = (bf16*)(ws + 67108864);
  bf16* v = (bf16*)(ws + 134217728);

  if (ws_size >= WS_NEED) {
    // -------- atomic-free path --------
    bf16* Ow    = (bf16*)(ws + 201326592);
    float* dp   = (float*)(ws + 268435456);
    bf16* Wt_w  = (bf16*)(ws + 285212672);
    bf16* Wt_h  = Wt_w + 98304;
    bf16* Wo_w  = Wt_h + 98304;
    bf16* Wo_h  = Wo_w + 32768;
    bf16* P     = q;   // q dead after k_dots_s
    bf16* Oh    = k;   // k dead after k_dots_s

    k_wt2<<<1024, 256, 0, stream>>>(Wq_w, Wkv_w, Wq_h, Wkv_h, Wout_w, Wout_h,
                                    Wt_w, Wt_h, Wo_w, Wo_h);
    // width phase (w-major q/k/v)
    k_qkv_mfma<<<1024, 256, 0, stream>>>(x, Wt_w, q, k, v, 1);
    k_width_attn_o<<<dim3(WW, NHEADS), 256, 0, stream>>>(q, k, v, Ow);
    // height phase (h-major q/k/v)
    k_qkv_mfma<<<1024, 256, 0, stream>>>(x, Wt_h, q, k, v, 0);
    k_dots_s<<<dim3(16, NHEADS, 8), 256, 0, stream>>>(q, k, dp);
    k_pb<<<65536 / 4, 256, 0, stream>>>(pair, ln_g, ln_b, W_pair, dp);  // into slice 0
    k_softmax8<<<dim3(256, NHEADS), 256, 0, stream>>>(dp, P);
    k_h_pv_o<<<dim3(HH, NHEADS), 256, 0, stream>>>(P, v, Oh);
    // fused final projection (sole writer of out)
    k_outproj<<<1024, 256, 0, stream>>>(Ow, Oh, Wo_w, Wo_h, bout_w, bout_h, out);
  } else {
    // -------- fallback: proven r4 path --------
    float* dots = (float*)(ws + 201326592);
    bf16* P = q;
    bf16* Wt_w = (bf16*)dots;
    bf16* Wt_h = Wt_w + 98304;

    k_wt<<<768, 256, 0, stream>>>(Wq_w, Wkv_w, Wq_h, Wkv_h, Wt_w, Wt_h);
    k_init_out<<<NROWS * 64 / 256, 256, 0, stream>>>(bout_w, bout_h, out);

    k_qkv_mfma<<<1024, 256, 0, stream>>>(x, Wt_w, q, k, v, 1);
    k_width_attn<<<dim3(WW, NHEADS), 256, 0, stream>>>(q, k, v, Wout_w, out);

    k_qkv_mfma<<<1024, 256, 0, stream>>>(x, Wt_h, q, k, v, 0);
    hipMemsetAsync(dots, 0, (size_t)8 * 65536 * sizeof(float), stream);
    k_dots<<<dim3(4, NHEADS, 16), 256, 0, stream>>>(q, k, dots);
    k_pb<<<65536 / 4, 256, 0, stream>>>(pair, ln_g, ln_b, W_pair, dots);
    k_softmax<<<dim3(256, NHEADS), 256, 0, stream>>>(dots, P);
    k_h_pv<<<dim3(HH, NHEADS), 256, 0, stream>>>(P, v, Wout_h, out);
  }
}

// Round 6
// 622.279 us; speedup vs baseline: 1.0697x; 1.0697x over previous
//
#include <hip/hip_runtime.h>
#include <hip/hip_bf16.h>

typedef __hip_bfloat16 bf16;
typedef __attribute__((ext_vector_type(8))) short bf16x8;
typedef __attribute__((ext_vector_type(4))) float f32x4;

#define MFMA16(a, b, c) __builtin_amdgcn_mfma_f32_16x16x32_bf16(a, b, c, 0, 0, 0)

// Problem constants (B=1)
#define HH 256
#define WW 256
#define NHEADS 8
#define NROWS 65536

// ws layout (203,423,744 B total -- PROVEN available since R1):
//   R0 @ 0          (67108864): width q (w-major)  -> Ow written IN PLACE (w-major)
//   R1 @ 67108864   (67108864): width k -> height q2 -> height v
//   R2 @ 134217728  (67108864): width v -> height k2 -> Oh (h-major)
//   R3 @ 201326592  (2097152):  Wt (384K, width then height) @+0
//                               P bf16 (1M) @+393216
//                               Wo_w/Wo_h bf16 [64][512] (128K) @+1441792
//   d_out (16,777,216 B) doubles as split-K dots scratch dp (8 x 2MB) before
//   k_outproj overwrites it with the final result.
//
// MFMA fragment conventions (verified m89/m91/m120):
//   A-frag: lane l holds A[m = l&15][k = (l>>4)*8 + t], t=0..7
//   B-frag: lane l holds B[n = l&15][k = (l>>4)*8 + t]
//   C/D   : lane l, reg r -> (col = l&15, row = (l>>4)*4 + r)
//   D[m][n] = sum_k A[m][k]*B[n][k]

__device__ __forceinline__ bf16x8 cvt8(const float* f) {
  bf16x8 r;
  bf16* h = (bf16*)&r;
#pragma unroll
  for (int i = 0; i < 8; i++) h[i] = __float2bfloat16(f[i]);
  return r;
}

// ---------------------------------------------------------------- Wq|Wkv transpose -> bf16 [1536][64]
__global__ void __launch_bounds__(256) k_wt1(const float* __restrict__ Wq,
                                             const float* __restrict__ Wkv,
                                             bf16* __restrict__ Wt) {
  const int idx = blockIdx.x * 256 + threadIdx.x;  // [0, 98304)
  const int k = idx / 1536, c = idx - k * 1536;
  const float val = (c < 512) ? Wq[k * 512 + c] : Wkv[k * 1024 + (c - 512)];
  Wt[(size_t)c * 64 + k] = __float2bfloat16(val);
}

// ---------------------------------------------------------------- Wout transpose -> bf16 [64][512]
__global__ void __launch_bounds__(256) k_wo(const float* __restrict__ Wout_w,
                                            const float* __restrict__ Wout_h,
                                            bf16* __restrict__ Wo_w,
                                            bf16* __restrict__ Wo_h) {
  int idx = blockIdx.x * 256 + threadIdx.x;  // [0, 65536)
  const float* W = Wout_w;
  bf16* dst = Wo_w;
  if (idx >= 32768) { idx -= 32768; W = Wout_h; dst = Wo_h; }
  const int c = idx >> 9, d = idx & 511;
  dst[idx] = __float2bfloat16(W[d * 64 + c]);  // Wo[c][d] = Wout[d][c]
}

// ---------------------------------------------------------------- QKV via MFMA (column-range variant)
// swap=1 -> rows written w-major (w*256+h). cg in [cg_lo,cg_hi): 0-3 -> d0, 4-7 -> d1, 8-11 -> d2.
__global__ void __launch_bounds__(256) k_qkv_mfma(const float* __restrict__ x,
                                                  const bf16* __restrict__ Wt,
                                                  bf16* __restrict__ d0,
                                                  bf16* __restrict__ d1,
                                                  bf16* __restrict__ d2,
                                                  int swap, int cg_lo, int cg_hi) {
  const int tid = threadIdx.x, lane = tid & 63, wv = tid >> 6;
  const int m16 = lane & 15, kq = lane >> 4;
  const int rowA = blockIdx.x * 64 + wv * 16 + m16;
  const int rowC0 = blockIdx.x * 64 + wv * 16 + kq * 4;

  const float* xr = x + (size_t)rowA * 64;
  float xf[8];
  bf16x8 af[2];
  *(float4*)&xf[0] = *(const float4*)(xr + kq * 8);
  *(float4*)&xf[4] = *(const float4*)(xr + kq * 8 + 4);
  af[0] = cvt8(xf);
  *(float4*)&xf[0] = *(const float4*)(xr + 32 + kq * 8);
  *(float4*)&xf[4] = *(const float4*)(xr + 32 + kq * 8 + 4);
  af[1] = cvt8(xf);

  size_t rbase[4];
#pragma unroll
  for (int r = 0; r < 4; r++) {
    const int rc = rowC0 + r;
    const int rr = swap ? (((rc & 255) << 8) | (rc >> 8)) : rc;
    rbase[r] = (size_t)rr * 512;
  }

#pragma unroll 1
  for (int cg = cg_lo; cg < cg_hi; cg++) {
    bf16* dst = (cg < 4) ? d0 : (cg < 8) ? d1 : d2;
    const int cbase = (cg & 3) * 128;
#pragma unroll
    for (int ct = 0; ct < 8; ct++) {
      const bf16* wp = Wt + (size_t)(cg * 128 + ct * 16 + m16) * 64 + kq * 8;
      const bf16x8 b0 = *(const bf16x8*)wp;
      const bf16x8 b1 = *(const bf16x8*)(wp + 32);
      f32x4 a = (f32x4){0.f, 0.f, 0.f, 0.f};
      a = MFMA16(af[0], b0, a);
      a = MFMA16(af[1], b1, a);
      const int cloc = cbase + ct * 16 + m16;
#pragma unroll
      for (int r = 0; r < 4; r++)
        dst[rbase[r] + cloc] = __float2bfloat16(a[r]);
    }
  }
}

// ---------------------------------------------------------------- width attention, atomic-free
// Inputs w-major. Writes Ow IN PLACE over q (w-major): each wave's stores hit exactly
// the rows/cols it register-preloaded from q -> race-free. NO __restrict__ on q/Ow.
// LDS 53248: Vt[64][256] XOR-swizzled @0 | Ps[wave][64][40] @32768.
__global__ void __launch_bounds__(256, 2)
k_width_attn_o(const bf16* q, const bf16* __restrict__ kk,
               const bf16* __restrict__ v, bf16* Ow) {
  __shared__ __align__(16) char smem[53248];
  bf16* Vt = (bf16*)smem;
  const int w = blockIdx.x, head = blockIdx.y;
  const int tid = threadIdx.x, lane = tid & 63, wv = tid >> 6;
  bf16* Ps = (bf16*)(smem + 32768 + wv * 5120);
  const int m16 = lane & 15, kq = lane >> 4;

  {  // Vt[d][jOct^(d&7)][j&7] = V[j][d]
    const bf16* src = v + ((size_t)(w * 256 + tid) * 512 + head * 64);
    uint4 rr[8];
#pragma unroll
    for (int c = 0; c < 8; c++) rr[c] = ((const uint4*)src)[c];
    const int jl = tid & 7, jh = tid >> 3;
#pragma unroll
    for (int c = 0; c < 8; c++) {
      const bf16* e = (const bf16*)&rr[c];
#pragma unroll
      for (int t = 0; t < 8; t++) {
        const int d = c * 8 + t;
        Vt[d * 256 + ((jh ^ (d & 7)) << 3) + jl] = e[t];
      }
    }
  }
  bf16x8 qf[4][2];
  const int i0 = wv * 64;
#pragma unroll
  for (int it = 0; it < 4; it++) {
    const bf16* b = q + ((size_t)(w * 256 + i0 + it * 16 + m16) * 512 + head * 64 + kq * 8);
    qf[it][0] = *(const bf16x8*)b;
    qf[it][1] = *(const bf16x8*)(b + 32);
  }
  __syncthreads();

  f32x4 acc[4][4];
#pragma unroll
  for (int a = 0; a < 4; a++)
#pragma unroll
    for (int b = 0; b < 4; b++) acc[a][b] = (f32x4){0.f, 0.f, 0.f, 0.f};
  float rsum[4][4];
#pragma unroll
  for (int a = 0; a < 4; a++)
#pragma unroll
    for (int r = 0; r < 4; r++) rsum[a][r] = 0.f;

  auto loadK = [&](int jc, bf16x8 kf[2][2]) {
#pragma unroll
    for (int jt = 0; jt < 2; jt++) {
      const bf16* b = kk + ((size_t)(w * 256 + jc * 32 + jt * 16 + m16) * 512 + head * 64 + kq * 8);
      kf[jt][0] = *(const bf16x8*)b;
      kf[jt][1] = *(const bf16x8*)(b + 32);
    }
  };
  bf16x8 kcur[2][2];
  loadK(0, kcur);

#pragma unroll 1
  for (int jc = 0; jc < 8; jc++) {
    bf16x8 knext[2][2];
    if (jc < 7) loadK(jc + 1, knext);
#pragma unroll
    for (int it = 0; it < 4; it++)
#pragma unroll
      for (int jt = 0; jt < 2; jt++) {
        f32x4 s = (f32x4){0.f, 0.f, 0.f, 0.f};
        s = MFMA16(qf[it][0], kcur[jt][0], s);
        s = MFMA16(qf[it][1], kcur[jt][1], s);
#pragma unroll
        for (int r = 0; r < 4; r++) {
          float p = __expf(s[r] * 0.125f);
          rsum[it][r] += p;
          Ps[(it * 16 + kq * 4 + r) * 40 + jt * 16 + m16] = __float2bfloat16(p);
        }
      }
    bf16x8 pf[4], vf[4];
#pragma unroll
    for (int it = 0; it < 4; it++)
      pf[it] = *(const bf16x8*)&Ps[(it * 16 + m16) * 40 + kq * 8];
#pragma unroll
    for (int dt = 0; dt < 4; dt++)
      vf[dt] = *(const bf16x8*)&Vt[(dt * 16 + m16) * 256 + (((jc * 4 + kq) ^ (m16 & 7)) << 3)];
#pragma unroll
    for (int it = 0; it < 4; it++)
#pragma unroll
      for (int dt = 0; dt < 4; dt++) acc[it][dt] = MFMA16(pf[it], vf[dt], acc[it][dt]);
    if (jc < 7) {
#pragma unroll
      for (int jt = 0; jt < 2; jt++) {
        kcur[jt][0] = knext[jt][0];
        kcur[jt][1] = knext[jt][1];
      }
    }
  }

#pragma unroll
  for (int it = 0; it < 4; it++)
#pragma unroll
    for (int r = 0; r < 4; r++) {
      float s = rsum[it][r];
      s += __shfl_xor(s, 1); s += __shfl_xor(s, 2);
      s += __shfl_xor(s, 4); s += __shfl_xor(s, 8);
      rsum[it][r] = 1.f / s;
    }
  // normalized O -> Ow (w-major, in place over q), plain posted stores
#pragma unroll
  for (int it = 0; it < 4; it++)
#pragma unroll
    for (int dt = 0; dt < 4; dt++)
#pragma unroll
      for (int r = 0; r < 4; r++) {
        const int i = i0 + it * 16 + kq * 4 + r;  // = h
        Ow[((size_t)(w * 256 + i)) * 512 + head * 64 + dt * 16 + m16] =
            __float2bfloat16(acc[it][dt][r] * rsum[it][r]);
      }
}

// ---------------------------------------------------------------- height tied dots, split-K, plain stores
// grid (16 tiles 64x64, 8 heads, 8 rc), block 256 = 4 waves (16 i-rows each).
__global__ void __launch_bounds__(256, 2)
k_dots_s(const bf16* __restrict__ q, const bf16* __restrict__ kk, float* __restrict__ dp) {
  __shared__ __align__(16) bf16 Qs[64 * 72];
  __shared__ __align__(16) bf16 Ks[64 * 72];
  const int tile = blockIdx.x, head = blockIdx.y, rc = blockIdx.z;
  const int i0 = (tile >> 2) * 64, j0 = (tile & 3) * 64;
  const int tid = threadIdx.x, lane = tid & 63, wv = tid >> 6;
  const int m16 = lane & 15, kq = lane >> 4;
  float* slice = dp + (size_t)rc * 524288 + (size_t)head * 65536;

  f32x4 acc[4];
#pragma unroll
  for (int b = 0; b < 4; b++) acc[b] = (f32x4){0.f, 0.f, 0.f, 0.f};

  const int row = tid >> 2, ch = (tid & 3) * 16;
#pragma unroll 1
  for (int rr = 0; rr < 32; rr++) {
    const int rrow = rc * 32 + rr;
    __syncthreads();
    {
      const bf16* qsrc = q + ((size_t)(rrow * 256 + i0 + row) * 512 + head * 64 + ch);
      const bf16* ksrc = kk + ((size_t)(rrow * 256 + j0 + row) * 512 + head * 64 + ch);
      *(uint4*)&Qs[row * 72 + ch] = *(const uint4*)qsrc;
      *(uint4*)&Qs[row * 72 + ch + 8] = *(const uint4*)(qsrc + 8);
      *(uint4*)&Ks[row * 72 + ch] = *(const uint4*)ksrc;
      *(uint4*)&Ks[row * 72 + ch + 8] = *(const uint4*)(ksrc + 8);
    }
    __syncthreads();
#pragma unroll
    for (int ks = 0; ks < 2; ks++) {
      bf16x8 af = *(const bf16x8*)&Qs[(wv * 16 + m16) * 72 + ks * 32 + kq * 8];
      bf16x8 bfr[4];
#pragma unroll
      for (int jt = 0; jt < 4; jt++)
        bfr[jt] = *(const bf16x8*)&Ks[(jt * 16 + m16) * 72 + ks * 32 + kq * 8];
#pragma unroll
      for (int jt = 0; jt < 4; jt++) acc[jt] = MFMA16(af, bfr[jt], acc[jt]);
    }
  }
  const float sc = 1.f / 128.f;  // dh^-0.5 * H^-0.5
#pragma unroll
  for (int jt = 0; jt < 4; jt++)
#pragma unroll
    for (int r = 0; r < 4; r++)
      slice[(size_t)(i0 + wv * 16 + kq * 4 + r) * 256 + j0 + jt * 16 + m16] = acc[jt][r] * sc;
}

// ---------------------------------------------------------------- pair bias: LN + @W_pair -> dp slice 0
__global__ void __launch_bounds__(256) k_pb(const float* __restrict__ pb,
                                            const float* __restrict__ g,
                                            const float* __restrict__ bb,
                                            const float* __restrict__ Wp,
                                            float* __restrict__ dots) {
  __shared__ float sn[4][128];
  const int tid = threadIdx.x, lane = tid & 63, wv = tid >> 6;
  const size_t ij = (size_t)blockIdx.x * 4 + wv;
  const float2 xv = *(const float2*)(pb + ij * 128 + lane * 2);

  float s = xv.x + xv.y;
#pragma unroll
  for (int o = 1; o < 64; o <<= 1) s += __shfl_xor(s, o);
  const float mu = s * (1.f / 128.f);
  const float d0 = xv.x - mu, d1 = xv.y - mu;
  float s2 = d0 * d0 + d1 * d1;
#pragma unroll
  for (int o = 1; o < 64; o <<= 1) s2 += __shfl_xor(s2, o);
  const float inv = rsqrtf(s2 * (1.f / 128.f) + 1e-5f);

  sn[wv][lane * 2 + 0] = d0 * inv * g[lane * 2 + 0] + bb[lane * 2 + 0];
  sn[wv][lane * 2 + 1] = d1 * inv * g[lane * 2 + 1] + bb[lane * 2 + 1];

  const int h = lane & 7, gp = lane >> 3;
  float a = 0.f;
#pragma unroll
  for (int p0 = 0; p0 < 16; p0++) {
    const int p = gp * 16 + p0;
    a += sn[wv][p] * Wp[p * 8 + h];
  }
  a += __shfl_xor(a, 8);
  a += __shfl_xor(a, 16);
  a += __shfl_xor(a, 32);
  if (lane < 8) dots[(size_t)h * 65536 + ij] += a;
}

// ---------------------------------------------------------------- softmax summing 8 split-K slices -> bf16 P
__global__ void __launch_bounds__(256) k_softmax8(const float* __restrict__ dp,
                                                  bf16* __restrict__ P) {
  __shared__ float red[4];
  const int i = blockIdx.x, head = blockIdx.y, t = threadIdx.x;
  const size_t base = (size_t)head * 65536 + i * 256 + t;
  float lg = 0.f;
#pragma unroll
  for (int s = 0; s < 8; s++) lg += dp[(size_t)s * 524288 + base];
  const float e = __expf(lg);
  float s = e;
#pragma unroll
  for (int o = 1; o < 64; o <<= 1) s += __shfl_xor(s, o);
  if ((t & 63) == 0) red[t >> 6] = s;
  __syncthreads();
  const float S = red[0] + red[1] + red[2] + red[3];
  P[base] = __float2bfloat16(e / S);
}

// ---------------------------------------------------------------- height PV, atomic-free -> Oh (h-major)
// LDS 32768: Vt[64][256] swizzled.
__global__ void __launch_bounds__(256, 2)
k_h_pv_o(const bf16* __restrict__ P, const bf16* __restrict__ v, bf16* __restrict__ Oh) {
  __shared__ __align__(16) bf16 Vt[64 * 256];
  const int r = blockIdx.x, head = blockIdx.y;
  const int tid = threadIdx.x, lane = tid & 63, wv = tid >> 6;
  const int m16 = lane & 15, kq = lane >> 4;

  {
    const bf16* src = v + ((size_t)(r * 256 + tid) * 512 + head * 64);
    uint4 rr[8];
#pragma unroll
    for (int c = 0; c < 8; c++) rr[c] = ((const uint4*)src)[c];
    const int jl = tid & 7, jh = tid >> 3;
#pragma unroll
    for (int c = 0; c < 8; c++) {
      const bf16* e = (const bf16*)&rr[c];
#pragma unroll
      for (int t = 0; t < 8; t++) {
        const int d = c * 8 + t;
        Vt[d * 256 + ((jh ^ (d & 7)) << 3) + jl] = e[t];
      }
    }
  }

  const bf16* Pb = P + (size_t)head * 65536;
  const int i0 = wv * 64;
  auto loadP = [&](int ks, bf16x8 pf[4]) {
#pragma unroll
    for (int it = 0; it < 4; it++)
      pf[it] = *(const bf16x8*)(Pb + (size_t)(i0 + it * 16 + m16) * 256 + ks * 32 + kq * 8);
  };
  bf16x8 pcur[4];
  loadP(0, pcur);
  __syncthreads();

  f32x4 acc[4][4];
#pragma unroll
  for (int a = 0; a < 4; a++)
#pragma unroll
    for (int b = 0; b < 4; b++) acc[a][b] = (f32x4){0.f, 0.f, 0.f, 0.f};

#pragma unroll 1
  for (int ks = 0; ks < 8; ks++) {
    bf16x8 pnext[4];
    if (ks < 7) loadP(ks + 1, pnext);
    bf16x8 vf[4];
#pragma unroll
    for (int dt = 0; dt < 4; dt++)
      vf[dt] = *(const bf16x8*)&Vt[(dt * 16 + m16) * 256 + (((ks * 4 + kq) ^ (m16 & 7)) << 3)];
#pragma unroll
    for (int it = 0; it < 4; it++)
#pragma unroll
      for (int dt = 0; dt < 4; dt++) acc[it][dt] = MFMA16(pcur[it], vf[dt], acc[it][dt]);
    if (ks < 7) {
#pragma unroll
      for (int it = 0; it < 4; it++) pcur[it] = pnext[it];
    }
  }
#pragma unroll
  for (int it = 0; it < 4; it++)
#pragma unroll
    for (int dt = 0; dt < 4; dt++)
#pragma unroll
      for (int r2 = 0; r2 < 4; r2++) {
        const int i = i0 + it * 16 + kq * 4 + r2;  // w position
        Oh[((size_t)(r * 256 + i)) * 512 + head * 64 + dt * 16 + m16] =
            __float2bfloat16(acc[it][dt][r2]);
      }
}

// ---------------------------------------------------------------- final fused projection
// out[n] = 0.5*(Ow@Wout_w + Oh@Wout_h)[n] + 0.5*(bw+bh); n = h*256+w (h-major).
// Ow is w-major: its row for out-row n is ((n&255)<<8)|(n>>8).
__global__ void __launch_bounds__(256) k_outproj(const bf16* __restrict__ Ow,
                                                 const bf16* __restrict__ Oh,
                                                 const bf16* __restrict__ Wow,  // [64][512]
                                                 const bf16* __restrict__ Woh,
                                                 const float* __restrict__ bw,
                                                 const float* __restrict__ bh,
                                                 float* __restrict__ out) {
  const int tid = threadIdx.x, lane = tid & 63, wv = tid >> 6;
  const int m16 = lane & 15, kq = lane >> 4;
  const int nA = blockIdx.x * 64 + wv * 16 + m16;
  const int wA = ((nA & 255) << 8) | (nA >> 8);  // w-major remap for Ow

  const bf16* aw = Ow + (size_t)wA * 512 + kq * 8;
  const bf16* ah = Oh + (size_t)nA * 512 + kq * 8;

  f32x4 acc[4];
#pragma unroll
  for (int ct = 0; ct < 4; ct++) acc[ct] = (f32x4){0.f, 0.f, 0.f, 0.f};

#pragma unroll 1
  for (int kc = 0; kc < 16; kc++) {
    const bf16x8 afw = *(const bf16x8*)(aw + kc * 32);
    const bf16x8 afh = *(const bf16x8*)(ah + kc * 32);
#pragma unroll
    for (int ct = 0; ct < 4; ct++) {
      const bf16x8 bfw = *(const bf16x8*)(Wow + (size_t)(ct * 16 + m16) * 512 + kc * 32 + kq * 8);
      const bf16x8 bfh = *(const bf16x8*)(Woh + (size_t)(ct * 16 + m16) * 512 + kc * 32 + kq * 8);
      acc[ct] = MFMA16(afw, bfw, acc[ct]);
      acc[ct] = MFMA16(afh, bfh, acc[ct]);
    }
  }
  const int n0 = blockIdx.x * 64 + wv * 16 + kq * 4;
#pragma unroll
  for (int ct = 0; ct < 4; ct++) {
    const int c = ct * 16 + m16;
    const float bias = 0.5f * (bw[c] + bh[c]);
#pragma unroll
    for (int r = 0; r < 4; r++)
      out[(size_t)(n0 + r) * 64 + c] = 0.5f * acc[ct][r] + bias;
  }
}

// ================================================================ launch
extern "C" void kernel_launch(void* const* d_in, const int* in_sizes, int n_in,
                              void* d_out, int out_size, void* d_ws, size_t ws_size,
                              hipStream_t stream) {
  const float* x      = (const float*)d_in[0];
  const float* pair   = (const float*)d_in[1];
  const float* Wq_w   = (const float*)d_in[2];
  const float* Wkv_w  = (const float*)d_in[3];
  const float* Wout_w = (const float*)d_in[4];
  const float* bout_w = (const float*)d_in[5];
  const float* Wq_h   = (const float*)d_in[6];
  const float* Wkv_h  = (const float*)d_in[7];
  const float* Wout_h = (const float*)d_in[8];
  const float* bout_h = (const float*)d_in[9];
  const float* ln_g   = (const float*)d_in[10];
  const float* ln_b   = (const float*)d_in[11];
  const float* W_pair = (const float*)d_in[12];
  float* out = (float*)d_out;

  char* ws = (char*)d_ws;
  bf16* R0 = (bf16*)ws;                     // width q -> Ow (in place)
  bf16* R1 = (bf16*)(ws + 67108864);        // width k -> height q2 -> height v
  bf16* R2 = (bf16*)(ws + 134217728);       // width v -> height k2 -> Oh
  bf16* Wt = (bf16*)(ws + 201326592);       // 384K
  bf16* P  = (bf16*)(ws + 201326592 + 393216);    // 1M
  bf16* Wo_w = (bf16*)(ws + 201326592 + 1441792); // 64K
  bf16* Wo_h = Wo_w + 32768;                      // 64K
  float* dp = out;                          // d_out doubles as split-K scratch (16MB exact)

  // -------- width attention phase (w-major q/k/v) --------
  k_wt1<<<384, 256, 0, stream>>>(Wq_w, Wkv_w, Wt);
  k_wo<<<256, 256, 0, stream>>>(Wout_w, Wout_h, Wo_w, Wo_h);
  k_qkv_mfma<<<1024, 256, 0, stream>>>(x, Wt, R0, R1, R2, 1, 0, 12);
  k_width_attn_o<<<dim3(WW, NHEADS), 256, 0, stream>>>(R0, R1, R2, R0);  // Ow over q

  // -------- height attention phase (h-major) --------
  k_wt1<<<384, 256, 0, stream>>>(Wq_h, Wkv_h, Wt);
  k_qkv_mfma<<<1024, 256, 0, stream>>>(x, Wt, R1, R2, R1, 0, 0, 8);   // q2->R1, k2->R2
  k_dots_s<<<dim3(16, NHEADS, 8), 256, 0, stream>>>(R1, R2, dp);
  k_qkv_mfma<<<1024, 256, 0, stream>>>(x, Wt, R1, R2, R1, 0, 8, 12);  // v->R1 (q2 dead)
  k_pb<<<65536 / 4, 256, 0, stream>>>(pair, ln_g, ln_b, W_pair, dp);  // into slice 0
  k_softmax8<<<dim3(256, NHEADS), 256, 0, stream>>>(dp, P);
  k_h_pv_o<<<dim3(HH, NHEADS), 256, 0, stream>>>(P, R1, R2);          // Oh over k2

  // -------- final fused projection (sole writer of out) --------
  k_outproj<<<1024, 256, 0, stream>>>(R0, R2, Wo_w, Wo_h, bout_w, bout_h, out);
}

// Round 7
// 605.830 us; speedup vs baseline: 1.0987x; 1.0271x over previous
//
#include <hip/hip_runtime.h>
#include <hip/hip_bf16.h>

typedef __hip_bfloat16 bf16;
typedef __attribute__((ext_vector_type(8))) short bf16x8;
typedef __attribute__((ext_vector_type(4))) float f32x4;

#define MFMA16(a, b, c) __builtin_amdgcn_mfma_f32_16x16x32_bf16(a, b, c, 0, 0, 0)

// Problem constants (B=1)
#define HH 256
#define WW 256
#define NHEADS 8
#define NROWS 65536

// ws layout (203,423,744 B total -- PROVEN available since R1):
//   R0 @ 0          (67108864): width q (w-major)  -> Ow written IN PLACE (w-major)
//   R1 @ 67108864   (67108864): width k -> height q2 -> height v
//   R2 @ 134217728  (67108864): width v -> height k2 -> Oh (h-major)
//   R3 @ 201326592  (2097152):  Wt (384K) @+0 | P bf16 (1M) @+393216 | Wo_w/Wo_h @+1441792
//   d_out (16,777,216 B) doubles as split-K dots scratch dp (8 x 2MB) before
//   k_outproj overwrites it with the final result.
//
// MFMA fragment conventions (verified m89/m91/m120):
//   A-frag: lane l holds A[m = l&15][k = (l>>4)*8 + t], t=0..7
//   B-frag: lane l holds B[n = l&15][k = (l>>4)*8 + t]
//   C/D   : lane l, reg r -> (col = l&15, row = (l>>4)*4 + r)
//   D[m][n] = sum_k A[m][k]*B[n][k]

__device__ __forceinline__ bf16x8 cvt8(const float* f) {
  bf16x8 r;
  bf16* h = (bf16*)&r;
#pragma unroll
  for (int i = 0; i < 8; i++) h[i] = __float2bfloat16(f[i]);
  return r;
}

// ---------------------------------------------------------------- Wq|Wkv transpose -> bf16 [1536][64]
__global__ void __launch_bounds__(256) k_wt1(const float* __restrict__ Wq,
                                             const float* __restrict__ Wkv,
                                             bf16* __restrict__ Wt) {
  const int idx = blockIdx.x * 256 + threadIdx.x;  // [0, 98304)
  const int k = idx / 1536, c = idx - k * 1536;
  const float val = (c < 512) ? Wq[k * 512 + c] : Wkv[k * 1024 + (c - 512)];
  Wt[(size_t)c * 64 + k] = __float2bfloat16(val);
}

// ---------------------------------------------------------------- Wout transpose -> bf16 [64][512]
__global__ void __launch_bounds__(256) k_wo(const float* __restrict__ Wout_w,
                                            const float* __restrict__ Wout_h,
                                            bf16* __restrict__ Wo_w,
                                            bf16* __restrict__ Wo_h) {
  int idx = blockIdx.x * 256 + threadIdx.x;  // [0, 65536)
  const float* W = Wout_w;
  bf16* dst = Wo_w;
  if (idx >= 32768) { idx -= 32768; W = Wout_h; dst = Wo_h; }
  const int c = idx >> 9, d = idx & 511;
  dst[idx] = __float2bfloat16(W[d * 64 + c]);  // Wo[c][d] = Wout[d][c]
}

// ---------------------------------------------------------------- QKV via MFMA, LDS-staged coalesced stores
// swap=1 -> rows written w-major (w*256+h). cg in [cg_lo,cg_hi): 0-3 -> d0, 4-7 -> d1, 8-11 -> d2.
// Per cg: C-tile (64x128) -> LDS bf16 (stride 136) -> cooperative uint4 writes
// (16 B/lane, 4 full 256B row-segments per wave-store) instead of 2 B/lane scatter.
__global__ void __launch_bounds__(256) k_qkv_mfma(const float* __restrict__ x,
                                                  const bf16* __restrict__ Wt,
                                                  bf16* __restrict__ d0,
                                                  bf16* __restrict__ d1,
                                                  bf16* __restrict__ d2,
                                                  int swap, int cg_lo, int cg_hi) {
  __shared__ __align__(16) bf16 Cs[64 * 136];  // 17408 B
  const int tid = threadIdx.x, lane = tid & 63, wv = tid >> 6;
  const int m16 = lane & 15, kq = lane >> 4;
  const int rowA = blockIdx.x * 64 + wv * 16 + m16;

  const float* xr = x + (size_t)rowA * 64;
  float xf[8];
  bf16x8 af[2];
  *(float4*)&xf[0] = *(const float4*)(xr + kq * 8);
  *(float4*)&xf[4] = *(const float4*)(xr + kq * 8 + 4);
  af[0] = cvt8(xf);
  *(float4*)&xf[0] = *(const float4*)(xr + 32 + kq * 8);
  *(float4*)&xf[4] = *(const float4*)(xr + 32 + kq * 8 + 4);
  af[1] = cvt8(xf);

  // per-thread global row mapping for the cooperative writes (4 rows/thread)
  size_t wrow[4];
#pragma unroll
  for (int s = 0; s < 4; s++) {
    const int row = (s * 256 + tid) >> 4;
    const int rc = blockIdx.x * 64 + row;
    const int rr = swap ? (((rc & 255) << 8) | (rc >> 8)) : rc;
    wrow[s] = (size_t)rr * 512;
  }
  const int ccol = (tid & 15) * 8;
  const int lrow0 = wv * 16 + kq * 4;

#pragma unroll 1
  for (int cg = cg_lo; cg < cg_hi; cg++) {
    bf16* dst = (cg < 4) ? d0 : (cg < 8) ? d1 : d2;
    const int cbase = (cg & 3) * 128;
#pragma unroll
    for (int ct = 0; ct < 8; ct++) {
      const bf16* wp = Wt + (size_t)(cg * 128 + ct * 16 + m16) * 64 + kq * 8;
      const bf16x8 b0 = *(const bf16x8*)wp;
      const bf16x8 b1 = *(const bf16x8*)(wp + 32);
      f32x4 a = (f32x4){0.f, 0.f, 0.f, 0.f};
      a = MFMA16(af[0], b0, a);
      a = MFMA16(af[1], b1, a);
#pragma unroll
      for (int r = 0; r < 4; r++)
        Cs[(lrow0 + r) * 136 + ct * 16 + m16] = __float2bfloat16(a[r]);
    }
    __syncthreads();
#pragma unroll
    for (int s = 0; s < 4; s++) {
      const int row = (s * 256 + tid) >> 4;
      *(uint4*)(dst + wrow[s] + cbase + ccol) = *(const uint4*)&Cs[row * 136 + ccol];
    }
    __syncthreads();
  }
}

// ---------------------------------------------------------------- width attention, atomic-free
// Inputs w-major. Writes Ow IN PLACE over q (w-major): each wave's stores hit exactly
// the rows/cols it register-preloaded from q -> race-free. NO __restrict__ on q/Ow.
// LDS 53248: Vt[64][256] XOR-swizzled @0 | Ps[wave][64][40] @32768.
__global__ void __launch_bounds__(256, 2)
k_width_attn_o(const bf16* q, const bf16* __restrict__ kk,
               const bf16* __restrict__ v, bf16* Ow) {
  __shared__ __align__(16) char smem[53248];
  bf16* Vt = (bf16*)smem;
  const int w = blockIdx.x, head = blockIdx.y;
  const int tid = threadIdx.x, lane = tid & 63, wv = tid >> 6;
  bf16* Ps = (bf16*)(smem + 32768 + wv * 5120);
  const int m16 = lane & 15, kq = lane >> 4;

  {  // Vt[d][jOct^(d&7)][j&7] = V[j][d]
    const bf16* src = v + ((size_t)(w * 256 + tid) * 512 + head * 64);
    uint4 rr[8];
#pragma unroll
    for (int c = 0; c < 8; c++) rr[c] = ((const uint4*)src)[c];
    const int jl = tid & 7, jh = tid >> 3;
#pragma unroll
    for (int c = 0; c < 8; c++) {
      const bf16* e = (const bf16*)&rr[c];
#pragma unroll
      for (int t = 0; t < 8; t++) {
        const int d = c * 8 + t;
        Vt[d * 256 + ((jh ^ (d & 7)) << 3) + jl] = e[t];
      }
    }
  }
  bf16x8 qf[4][2];
  const int i0 = wv * 64;
#pragma unroll
  for (int it = 0; it < 4; it++) {
    const bf16* b = q + ((size_t)(w * 256 + i0 + it * 16 + m16) * 512 + head * 64 + kq * 8);
    qf[it][0] = *(const bf16x8*)b;
    qf[it][1] = *(const bf16x8*)(b + 32);
  }
  __syncthreads();

  f32x4 acc[4][4];
#pragma unroll
  for (int a = 0; a < 4; a++)
#pragma unroll
    for (int b = 0; b < 4; b++) acc[a][b] = (f32x4){0.f, 0.f, 0.f, 0.f};
  float rsum[4][4];
#pragma unroll
  for (int a = 0; a < 4; a++)
#pragma unroll
    for (int r = 0; r < 4; r++) rsum[a][r] = 0.f;

  auto loadK = [&](int jc, bf16x8 kf[2][2]) {
#pragma unroll
    for (int jt = 0; jt < 2; jt++) {
      const bf16* b = kk + ((size_t)(w * 256 + jc * 32 + jt * 16 + m16) * 512 + head * 64 + kq * 8);
      kf[jt][0] = *(const bf16x8*)b;
      kf[jt][1] = *(const bf16x8*)(b + 32);
    }
  };
  bf16x8 kcur[2][2];
  loadK(0, kcur);

#pragma unroll 1
  for (int jc = 0; jc < 8; jc++) {
    bf16x8 knext[2][2];
    if (jc < 7) loadK(jc + 1, knext);
#pragma unroll
    for (int it = 0; it < 4; it++)
#pragma unroll
      for (int jt = 0; jt < 2; jt++) {
        f32x4 s = (f32x4){0.f, 0.f, 0.f, 0.f};
        s = MFMA16(qf[it][0], kcur[jt][0], s);
        s = MFMA16(qf[it][1], kcur[jt][1], s);
#pragma unroll
        for (int r = 0; r < 4; r++) {
          float p = __expf(s[r] * 0.125f);
          rsum[it][r] += p;
          Ps[(it * 16 + kq * 4 + r) * 40 + jt * 16 + m16] = __float2bfloat16(p);
        }
      }
    bf16x8 pf[4], vf[4];
#pragma unroll
    for (int it = 0; it < 4; it++)
      pf[it] = *(const bf16x8*)&Ps[(it * 16 + m16) * 40 + kq * 8];
#pragma unroll
    for (int dt = 0; dt < 4; dt++)
      vf[dt] = *(const bf16x8*)&Vt[(dt * 16 + m16) * 256 + (((jc * 4 + kq) ^ (m16 & 7)) << 3)];
#pragma unroll
    for (int it = 0; it < 4; it++)
#pragma unroll
      for (int dt = 0; dt < 4; dt++) acc[it][dt] = MFMA16(pf[it], vf[dt], acc[it][dt]);
    if (jc < 7) {
#pragma unroll
      for (int jt = 0; jt < 2; jt++) {
        kcur[jt][0] = knext[jt][0];
        kcur[jt][1] = knext[jt][1];
      }
    }
  }

#pragma unroll
  for (int it = 0; it < 4; it++)
#pragma unroll
    for (int r = 0; r < 4; r++) {
      float s = rsum[it][r];
      s += __shfl_xor(s, 1); s += __shfl_xor(s, 2);
      s += __shfl_xor(s, 4); s += __shfl_xor(s, 8);
      rsum[it][r] = 1.f / s;
    }
  // normalized O -> Ow (w-major, in place over q), plain posted stores
#pragma unroll
  for (int it = 0; it < 4; it++)
#pragma unroll
    for (int dt = 0; dt < 4; dt++)
#pragma unroll
      for (int r = 0; r < 4; r++) {
        const int i = i0 + it * 16 + kq * 4 + r;  // = h
        Ow[((size_t)(w * 256 + i)) * 512 + head * 64 + dt * 16 + m16] =
            __float2bfloat16(acc[it][dt][r] * rsum[it][r]);
      }
}

// ---------------------------------------------------------------- height tied dots, split-K, plain stores
// grid (16 tiles 64x64, 8 heads, 8 rc), block 256 = 4 waves (16 i-rows each).
__global__ void __launch_bounds__(256, 2)
k_dots_s(const bf16* __restrict__ q, const bf16* __restrict__ kk, float* __restrict__ dp) {
  __shared__ __align__(16) bf16 Qs[64 * 72];
  __shared__ __align__(16) bf16 Ks[64 * 72];
  const int tile = blockIdx.x, head = blockIdx.y, rc = blockIdx.z;
  const int i0 = (tile >> 2) * 64, j0 = (tile & 3) * 64;
  const int tid = threadIdx.x, lane = tid & 63, wv = tid >> 6;
  const int m16 = lane & 15, kq = lane >> 4;
  float* slice = dp + (size_t)rc * 524288 + (size_t)head * 65536;

  f32x4 acc[4];
#pragma unroll
  for (int b = 0; b < 4; b++) acc[b] = (f32x4){0.f, 0.f, 0.f, 0.f};

  const int row = tid >> 2, ch = (tid & 3) * 16;
#pragma unroll 1
  for (int rr = 0; rr < 32; rr++) {
    const int rrow = rc * 32 + rr;
    __syncthreads();
    {
      const bf16* qsrc = q + ((size_t)(rrow * 256 + i0 + row) * 512 + head * 64 + ch);
      const bf16* ksrc = kk + ((size_t)(rrow * 256 + j0 + row) * 512 + head * 64 + ch);
      *(uint4*)&Qs[row * 72 + ch] = *(const uint4*)qsrc;
      *(uint4*)&Qs[row * 72 + ch + 8] = *(const uint4*)(qsrc + 8);
      *(uint4*)&Ks[row * 72 + ch] = *(const uint4*)ksrc;
      *(uint4*)&Ks[row * 72 + ch + 8] = *(const uint4*)(ksrc + 8);
    }
    __syncthreads();
#pragma unroll
    for (int ks = 0; ks < 2; ks++) {
      bf16x8 af = *(const bf16x8*)&Qs[(wv * 16 + m16) * 72 + ks * 32 + kq * 8];
      bf16x8 bfr[4];
#pragma unroll
      for (int jt = 0; jt < 4; jt++)
        bfr[jt] = *(const bf16x8*)&Ks[(jt * 16 + m16) * 72 + ks * 32 + kq * 8];
#pragma unroll
      for (int jt = 0; jt < 4; jt++) acc[jt] = MFMA16(af, bfr[jt], acc[jt]);
    }
  }
  const float sc = 1.f / 128.f;  // dh^-0.5 * H^-0.5
#pragma unroll
  for (int jt = 0; jt < 4; jt++)
#pragma unroll
    for (int r = 0; r < 4; r++)
      slice[(size_t)(i0 + wv * 16 + kq * 4 + r) * 256 + j0 + jt * 16 + m16] = acc[jt][r] * sc;
}

// ---------------------------------------------------------------- pair bias: LN + @W_pair -> dp slice 0
__global__ void __launch_bounds__(256) k_pb(const float* __restrict__ pb,
                                            const float* __restrict__ g,
                                            const float* __restrict__ bb,
                                            const float* __restrict__ Wp,
                                            float* __restrict__ dots) {
  __shared__ float sn[4][128];
  const int tid = threadIdx.x, lane = tid & 63, wv = tid >> 6;
  const size_t ij = (size_t)blockIdx.x * 4 + wv;
  const float2 xv = *(const float2*)(pb + ij * 128 + lane * 2);

  float s = xv.x + xv.y;
#pragma unroll
  for (int o = 1; o < 64; o <<= 1) s += __shfl_xor(s, o);
  const float mu = s * (1.f / 128.f);
  const float d0 = xv.x - mu, d1 = xv.y - mu;
  float s2 = d0 * d0 + d1 * d1;
#pragma unroll
  for (int o = 1; o < 64; o <<= 1) s2 += __shfl_xor(s2, o);
  const float inv = rsqrtf(s2 * (1.f / 128.f) + 1e-5f);

  sn[wv][lane * 2 + 0] = d0 * inv * g[lane * 2 + 0] + bb[lane * 2 + 0];
  sn[wv][lane * 2 + 1] = d1 * inv * g[lane * 2 + 1] + bb[lane * 2 + 1];

  const int h = lane & 7, gp = lane >> 3;
  float a = 0.f;
#pragma unroll
  for (int p0 = 0; p0 < 16; p0++) {
    const int p = gp * 16 + p0;
    a += sn[wv][p] * Wp[p * 8 + h];
  }
  a += __shfl_xor(a, 8);
  a += __shfl_xor(a, 16);
  a += __shfl_xor(a, 32);
  if (lane < 8) dots[(size_t)h * 65536 + ij] += a;
}

// ---------------------------------------------------------------- softmax summing 8 split-K slices -> bf16 P
__global__ void __launch_bounds__(256) k_softmax8(const float* __restrict__ dp,
                                                  bf16* __restrict__ P) {
  __shared__ float red[4];
  const int i = blockIdx.x, head = blockIdx.y, t = threadIdx.x;
  const size_t base = (size_t)head * 65536 + i * 256 + t;
  float lg = 0.f;
#pragma unroll
  for (int s = 0; s < 8; s++) lg += dp[(size_t)s * 524288 + base];
  const float e = __expf(lg);
  float s = e;
#pragma unroll
  for (int o = 1; o < 64; o <<= 1) s += __shfl_xor(s, o);
  if ((t & 63) == 0) red[t >> 6] = s;
  __syncthreads();
  const float S = red[0] + red[1] + red[2] + red[3];
  P[base] = __float2bfloat16(e / S);
}

// ---------------------------------------------------------------- height PV, atomic-free -> Oh (h-major)
// LDS 32768: Vt[64][256] swizzled.
__global__ void __launch_bounds__(256, 2)
k_h_pv_o(const bf16* __restrict__ P, const bf16* __restrict__ v, bf16* __restrict__ Oh) {
  __shared__ __align__(16) bf16 Vt[64 * 256];
  const int r = blockIdx.x, head = blockIdx.y;
  const int tid = threadIdx.x, lane = tid & 63, wv = tid >> 6;
  const int m16 = lane & 15, kq = lane >> 4;

  {
    const bf16* src = v + ((size_t)(r * 256 + tid) * 512 + head * 64);
    uint4 rr[8];
#pragma unroll
    for (int c = 0; c < 8; c++) rr[c] = ((const uint4*)src)[c];
    const int jl = tid & 7, jh = tid >> 3;
#pragma unroll
    for (int c = 0; c < 8; c++) {
      const bf16* e = (const bf16*)&rr[c];
#pragma unroll
      for (int t = 0; t < 8; t++) {
        const int d = c * 8 + t;
        Vt[d * 256 + ((jh ^ (d & 7)) << 3) + jl] = e[t];
      }
    }
  }

  const bf16* Pb = P + (size_t)head * 65536;
  const int i0 = wv * 64;
  auto loadP = [&](int ks, bf16x8 pf[4]) {
#pragma unroll
    for (int it = 0; it < 4; it++)
      pf[it] = *(const bf16x8*)(Pb + (size_t)(i0 + it * 16 + m16) * 256 + ks * 32 + kq * 8);
  };
  bf16x8 pcur[4];
  loadP(0, pcur);
  __syncthreads();

  f32x4 acc[4][4];
#pragma unroll
  for (int a = 0; a < 4; a++)
#pragma unroll
    for (int b = 0; b < 4; b++) acc[a][b] = (f32x4){0.f, 0.f, 0.f, 0.f};

#pragma unroll 1
  for (int ks = 0; ks < 8; ks++) {
    bf16x8 pnext[4];
    if (ks < 7) loadP(ks + 1, pnext);
    bf16x8 vf[4];
#pragma unroll
    for (int dt = 0; dt < 4; dt++)
      vf[dt] = *(const bf16x8*)&Vt[(dt * 16 + m16) * 256 + (((ks * 4 + kq) ^ (m16 & 7)) << 3)];
#pragma unroll
    for (int it = 0; it < 4; it++)
#pragma unroll
      for (int dt = 0; dt < 4; dt++) acc[it][dt] = MFMA16(pcur[it], vf[dt], acc[it][dt]);
    if (ks < 7) {
#pragma unroll
      for (int it = 0; it < 4; it++) pcur[it] = pnext[it];
    }
  }
#pragma unroll
  for (int it = 0; it < 4; it++)
#pragma unroll
    for (int dt = 0; dt < 4; dt++)
#pragma unroll
      for (int r2 = 0; r2 < 4; r2++) {
        const int i = i0 + it * 16 + kq * 4 + r2;  // w position
        Oh[((size_t)(r * 256 + i)) * 512 + head * 64 + dt * 16 + m16] =
            __float2bfloat16(acc[it][dt][r2]);
      }
}

// ---------------------------------------------------------------- final fused projection
// out[n] = 0.5*(Ow@Wout_w + Oh@Wout_h)[n] + 0.5*(bw+bh); n = h*256+w (h-major).
// Ow is w-major: its row for out-row n is ((n&255)<<8)|(n>>8).
__global__ void __launch_bounds__(256) k_outproj(const bf16* __restrict__ Ow,
                                                 const bf16* __restrict__ Oh,
                                                 const bf16* __restrict__ Wow,  // [64][512]
                                                 const bf16* __restrict__ Woh,
                                                 const float* __restrict__ bw,
                                                 const float* __restrict__ bh,
                                                 float* __restrict__ out) {
  const int tid = threadIdx.x, lane = tid & 63, wv = tid >> 6;
  const int m16 = lane & 15, kq = lane >> 4;
  const int nA = blockIdx.x * 64 + wv * 16 + m16;
  const int wA = ((nA & 255) << 8) | (nA >> 8);  // w-major remap for Ow

  const bf16* aw = Ow + (size_t)wA * 512 + kq * 8;
  const bf16* ah = Oh + (size_t)nA * 512 + kq * 8;

  f32x4 acc[4];
#pragma unroll
  for (int ct = 0; ct < 4; ct++) acc[ct] = (f32x4){0.f, 0.f, 0.f, 0.f};

#pragma unroll 1
  for (int kc = 0; kc < 16; kc++) {
    const bf16x8 afw = *(const bf16x8*)(aw + kc * 32);
    const bf16x8 afh = *(const bf16x8*)(ah + kc * 32);
#pragma unroll
    for (int ct = 0; ct < 4; ct++) {
      const bf16x8 bfw = *(const bf16x8*)(Wow + (size_t)(ct * 16 + m16) * 512 + kc * 32 + kq * 8);
      const bf16x8 bfh = *(const bf16x8*)(Woh + (size_t)(ct * 16 + m16) * 512 + kc * 32 + kq * 8);
      acc[ct] = MFMA16(afw, bfw, acc[ct]);
      acc[ct] = MFMA16(afh, bfh, acc[ct]);
    }
  }
  const int n0 = blockIdx.x * 64 + wv * 16 + kq * 4;
#pragma unroll
  for (int ct = 0; ct < 4; ct++) {
    const int c = ct * 16 + m16;
    const float bias = 0.5f * (bw[c] + bh[c]);
#pragma unroll
    for (int r = 0; r < 4; r++)
      out[(size_t)(n0 + r) * 64 + c] = 0.5f * acc[ct][r] + bias;
  }
}

// ================================================================ launch
extern "C" void kernel_launch(void* const* d_in, const int* in_sizes, int n_in,
                              void* d_out, int out_size, void* d_ws, size_t ws_size,
                              hipStream_t stream) {
  const float* x      = (const float*)d_in[0];
  const float* pair   = (const float*)d_in[1];
  const float* Wq_w   = (const float*)d_in[2];
  const float* Wkv_w  = (const float*)d_in[3];
  const float* Wout_w = (const float*)d_in[4];
  const float* bout_w = (const float*)d_in[5];
  const float* Wq_h   = (const float*)d_in[6];
  const float* Wkv_h  = (const float*)d_in[7];
  const float* Wout_h = (const float*)d_in[8];
  const float* bout_h = (const float*)d_in[9];
  const float* ln_g   = (const float*)d_in[10];
  const float* ln_b   = (const float*)d_in[11];
  const float* W_pair = (const float*)d_in[12];
  float* out = (float*)d_out;

  char* ws = (char*)d_ws;
  bf16* R0 = (bf16*)ws;                     // width q -> Ow (in place)
  bf16* R1 = (bf16*)(ws + 67108864);        // width k -> height q2 -> height v
  bf16* R2 = (bf16*)(ws + 134217728);       // width v -> height k2 -> Oh
  bf16* Wt = (bf16*)(ws + 201326592);       // 384K
  bf16* P  = (bf16*)(ws + 201326592 + 393216);    // 1M
  bf16* Wo_w = (bf16*)(ws + 201326592 + 1441792); // 64K
  bf16* Wo_h = Wo_w + 32768;                      // 64K
  float* dp = out;                          // d_out doubles as split-K scratch (16MB exact)

  // -------- width attention phase (w-major q/k/v) --------
  k_wt1<<<384, 256, 0, stream>>>(Wq_w, Wkv_w, Wt);
  k_wo<<<256, 256, 0, stream>>>(Wout_w, Wout_h, Wo_w, Wo_h);
  k_qkv_mfma<<<1024, 256, 0, stream>>>(x, Wt, R0, R1, R2, 1, 0, 12);
  k_width_attn_o<<<dim3(WW, NHEADS), 256, 0, stream>>>(R0, R1, R2, R0);  // Ow over q

  // -------- height attention phase (h-major) --------
  k_wt1<<<384, 256, 0, stream>>>(Wq_h, Wkv_h, Wt);
  k_qkv_mfma<<<1024, 256, 0, stream>>>(x, Wt, R1, R2, R1, 0, 0, 8);   // q2->R1, k2->R2
  k_dots_s<<<dim3(16, NHEADS, 8), 256, 0, stream>>>(R1, R2, dp);
  k_qkv_mfma<<<1024, 256, 0, stream>>>(x, Wt, R1, R2, R1, 0, 8, 12);  // v->R1 (q2 dead)
  k_pb<<<65536 / 4, 256, 0, stream>>>(pair, ln_g, ln_b, W_pair, dp);  // into slice 0
  k_softmax8<<<dim3(256, NHEADS), 256, 0, stream>>>(dp, P);
  k_h_pv_o<<<dim3(HH, NHEADS), 256, 0, stream>>>(P, R1, R2);          // Oh over k2

  // -------- final fused projection (sole writer of out) --------
  k_outproj<<<1024, 256, 0, stream>>>(R0, R2, Wo_w, Wo_h, bout_w, bout_h, out);
}